// Round 16
// baseline (412.139 us; speedup 1.0000x reference)
//
#include <hip/hip_runtime.h>
#include <cstdint>
#include <cstddef>

// ---------------------------------------------------------------------------
// NN_each_LN_exp: 33x33 SAME convs on 32x32 maps = dense 1024x1024 linear
// operators -> f16 MFMA GEMMs with fused epilogues. Row layout r = n*4+k:
// the 16x16x32 MFMA acc quad holds all 4 colors of one (n,o) cell.
// R16 (on R15's 398.1us): one-hot A-operands (Xe/Xn/Xz) precomputed in
// build_all's board section -> faA/faB become pure-async m97 GEMMs with
// zero in-loop expansion VALU. Single-variable probe: R6 tested precomputed
// one-hot only at the bad BN=256 shape; this is the proven 128^2 shape.
// ---------------------------------------------------------------------------

typedef _Float16 f16;
typedef __attribute__((ext_vector_type(8))) _Float16 f16x8;
typedef __attribute__((ext_vector_type(4))) float f32x4;

#define NB   4096
#define PIX  1024
#define MR   (NB * 4)

__device__ __forceinline__ void gld_lds16(const void* g, void* l) {
    __builtin_amdgcn_global_load_lds(
        (const __attribute__((address_space(1))) void*)g,
        (__attribute__((address_space(3))) void*)l, 16, 0, 0);
}

// Merged builds: [0,4096) conv mats, [4096,4608) W1 pad,
// [4608,5632) board transpose + one-hot Xe/Xn/Xz
__global__ void build_all(const float* __restrict__ we, const float* __restrict__ wn,
                          const float* __restrict__ wn2, const float* __restrict__ wem,
                          const float* __restrict__ W1, const int* __restrict__ dots,
                          f16* __restrict__ Me, f16* __restrict__ Mn,
                          f16* __restrict__ Mn2, f16* __restrict__ Mem,
                          f16* __restrict__ W1b, unsigned char* __restrict__ board,
                          f16* __restrict__ Xe, f16* __restrict__ Xn,
                          f16* __restrict__ Xz) {
    __shared__ unsigned char tile[64][68];
    int bi = blockIdx.x, t = threadIdx.x;
    if (bi < 4096) {
        int idx = bi * 256 + t;
        int o = idx >> 10, in = idx & 1023;
        int i = o >> 5, j = o & 31, a = in >> 5, b = in & 31;
        int u = a - i + 16, v = b - j + 16;
        bool ok = (u >= 0) && (u < 33) && (v >= 0) && (v < 33);
        int w = u * 33 + v;
        float ve = 0.f, vn = 0.f, vn2 = 0.f, vem = 0.f;
        if (ok) { ve = we[w]; vn = wn[w]; vn2 = wn2[w]; vem = wem[w]; }
        Me[idx]  = (f16)ve;
        Mn[idx]  = (f16)vn;
        Mn2[idx] = (f16)vn2;
        Mem[idx] = (f16)vem;
    } else if (bi < 4608) {
        int idx = (bi - 4096) * 256 + t;
        int j = idx >> 10, i = idx & 1023;
        W1b[idx] = (f16)(j < 100 ? W1[j * 1024 + i] : 0.f);
    } else {
        int bb = bi - 4608;
        int bp = bb & 15, bn = bb >> 4;
        int p0 = bp * 64, n0 = bn * 64;
        int ln = t & 63, lp = t >> 6;
#pragma unroll
        for (int j = 0; j < 16; j++) {
            int p = lp * 16 + j;
            tile[p][ln] = (unsigned char)dots[(size_t)(p0 + p) * 4096 + n0 + ln];
        }
        __syncthreads();
#pragma unroll
        for (int j = 0; j < 16; j++) {
            int n = lp * 16 + j;
            int c = tile[ln][n];
            size_t np = (size_t)(n0 + n) * 1024 + p0 + ln;
            board[np] = (unsigned char)c;
            Xz[np] = (f16)(c == 0 ? 1.f : 0.f);
            size_t r0 = (size_t)(4 * (n0 + n)) * 1024 + p0 + ln;
#pragma unroll
            for (int k = 0; k < 4; k++) {
                Xe[r0 + (size_t)k * 1024] = (f16)((c == k + 1) ? 1.f : 0.f);
                Xn[r0 + (size_t)k * 1024] = (f16)((c != 0 && c != k + 1) ? 1.f : 0.f);
            }
        }
    }
}

// ---------------------------------------------------------------------------
// Generic GEMM body: BM=BN=128, BK=64, 4 waves as 2x2, 16x16x32 MFMA,
// XOR-swizzled chunks (conflict-free frag reads). A pure-async (ASRC 0).
// MODE: 0 f16-out ldo
//       2 stage1 fused-mk_sa: L0 = asel + En - NCsel; Lsel=L0(f16);
//         Pout[4n+k] = NC[4n+k] * sigmoid(L0)
// ---------------------------------------------------------------------------
template <int MODE>
__device__ __forceinline__ void run_gemm(
    int bjob, int ypx, int nx, char* smem,
    const f16* __restrict__ X, const f16* __restrict__ B,
    const unsigned char* __restrict__ board, const f16* __restrict__ En,
    const f16* __restrict__ NCs, f16* __restrict__ Lsel,
    f16* __restrict__ Pout, f16* __restrict__ outB, int ldo) {
    char* smB = smem;                              // 16 KB
    char* smA = smem + 16384;

    const int tid = threadIdx.x;
    const int wv = tid >> 6, ln = tid & 63;
    const int wm = wv >> 1, wn_ = wv & 1;
    const int lr = ln & 15, lq = ln >> 4;

    int xcd = bjob & 7, slot = bjob >> 3;
    int bx = slot % nx;
    int by = xcd * ypx + slot / nx;
    const int rtile = by * 128, otile = bx * 128;

    const f32x4 fz = {0.f, 0.f, 0.f, 0.f};
    f32x4 acc[4][4];
#pragma unroll
    for (int i = 0; i < 4; i++)
#pragma unroll
        for (int j = 0; j < 4; j++) acc[i][j] = fz;

    for (int kb = 0; kb < 1024; kb += 64) {
#pragma unroll
        for (int t = 0; t < 4; t++) {
            int c = (wv * 4 + t) * 64 + ln;
            int row = c >> 3, gcol = (c & 7) ^ (row & 7);
            gld_lds16(B + (size_t)(otile + row) * 1024 + kb + gcol * 8, smB + c * 16);
            gld_lds16(X + (size_t)(rtile + row) * 1024 + kb + gcol * 8, smA + c * 16);
        }
        __syncthreads();

#pragma unroll
        for (int kk = 0; kk < 2; kk++) {
            const int oct = kk * 4 + lq;
            f16x8 af[4], bfr[4];
#pragma unroll
            for (int i = 0; i < 4; i++) {
                int rrow = wm * 64 + i * 16 + lr;
                af[i] = *(const f16x8*)(smA + rrow * 128 + (oct ^ (rrow & 7)) * 16);
            }
#pragma unroll
            for (int j = 0; j < 4; j++) {
                int brow = wn_ * 64 + j * 16 + lr;
                bfr[j] = *(const f16x8*)(smB + brow * 128 + (oct ^ (brow & 7)) * 16);
            }
#pragma unroll
            for (int i = 0; i < 4; i++)
#pragma unroll
                for (int j = 0; j < 4; j++)
                    acc[i][j] = __builtin_amdgcn_mfma_f32_16x16x32_f16(
                        af[i], bfr[j], acc[i][j], 0, 0, 0);
        }
        __syncthreads();
    }

#pragma unroll
    for (int i = 0; i < 4; i++) {
        int rbase = rtile + wm * 64 + i * 16 + lq * 4;
#pragma unroll
        for (int j = 0; j < 4; j++) {
            int o = otile + wn_ * 64 + j * 16 + lr;
            f32x4 a = acc[i][j];
            if (MODE == 0) {
#pragma unroll
                for (int v = 0; v < 4; v++)
                    outB[(size_t)(rbase + v) * ldo + o] = (f16)a[v];
            } else {                               // 2: fused stage1 + mk_sa
                int n = rbase >> 2;
                size_t no = (size_t)n * PIX + o;
                int c = board[no];
                float asel = (c == 1) ? a[0] : (c == 2) ? a[1] : (c == 3) ? a[2] : a[3];
                size_t r0 = (size_t)rbase * PIX + o;
                f16 nc0 = NCs[r0], nc1 = NCs[r0 + PIX];
                f16 nc2 = NCs[r0 + 2 * PIX], nc3 = NCs[r0 + 3 * PIX];
                float L = 0.f;
                if (c > 0) {
                    float ncsel = (float)((c == 1) ? nc0 : (c == 2) ? nc1
                                        : (c == 3) ? nc2 : nc3);
                    L = asel + (float)En[no] - ncsel;
                }
                Lsel[no] = (f16)L;
                f16 s = (f16)(1.f / (1.f + __expf(-L)));
                Pout[r0]           = nc0 * s;
                Pout[r0 + PIX]     = nc1 * s;
                Pout[r0 + 2 * PIX] = nc2 * s;
                Pout[r0 + 3 * PIX] = nc3 * s;
            }
        }
    }
}

// Phase A-a: [0,1024) NC (A=Xn), [1024,1280) En (A=Xz)
__global__ void __launch_bounds__(256, 4) gemm_faA(
    const f16* __restrict__ Xn, const f16* __restrict__ Xz,
    const f16* __restrict__ Mn, const f16* __restrict__ Mem,
    f16* __restrict__ NC, f16* __restrict__ En) {
    __shared__ __attribute__((aligned(16))) char smem[32768];
    int bi = blockIdx.x;
    if (bi < 1024) {
        run_gemm<0>(bi, 16, 8, smem, Xn, Mn, nullptr, nullptr, nullptr,
                    nullptr, nullptr, NC, PIX);
    } else {
        run_gemm<0>(bi - 1024, 4, 8, smem, Xz, Mem, nullptr, nullptr, nullptr,
                    nullptr, nullptr, En, PIX);
    }
}

// Phase A-b: stage1 GEMM (A=Xe) with fused mk_sa epilogue -> Lsel, P1
__global__ void __launch_bounds__(256, 4) gemm_faB(
    const f16* __restrict__ Xe, const f16* __restrict__ Me,
    const unsigned char* __restrict__ board,
    const f16* __restrict__ En, const f16* __restrict__ NC,
    f16* __restrict__ Lsel, f16* __restrict__ P1) {
    __shared__ __attribute__((aligned(16))) char smem[32768];
    run_gemm<2>(blockIdx.x, 16, 8, smem, Xe, Me, board, En, NC,
                Lsel, P1, nullptr, 0);
}

// ---------------------------------------------------------------------------
// Depth GEMM, pure-async (m97 structure): A = P_d, B = Mn2, both via
// global_load_lds. Epilogue: L += E + Csel, s = sigmoid; MODE 3 writes
// Lsel(f16) + P_{d+1} = NC * s; MODE 4 writes feat = s only.
// ---------------------------------------------------------------------------
template <int MODE>
__global__ void __launch_bounds__(256, 2) gemm_depth(
    const f16* __restrict__ Pin, const f16* __restrict__ Mn2,
    const unsigned char* __restrict__ board, const f16* __restrict__ NC,
    const f16* __restrict__ En, f16* __restrict__ Lsel,
    f16* __restrict__ Pout, f16* __restrict__ feat) {
    __shared__ __attribute__((aligned(16))) char smem[32768];
    char* smB = smem;
    char* smA = smem + 16384;

    const int tid = threadIdx.x;
    const int wv = tid >> 6, ln = tid & 63;
    const int wm = wv >> 1, wn_ = wv & 1;
    const int lr = ln & 15, lq = ln >> 4;

    int bi = blockIdx.x;
    int xcd = bi & 7, slot = bi >> 3;
    int bx = slot & 7;
    int by = xcd * 16 + (slot >> 3);
    const int rtile = by * 128, otile = bx * 128;

    const f32x4 fz = {0.f, 0.f, 0.f, 0.f};
    f32x4 acc[4][4];
#pragma unroll
    for (int i = 0; i < 4; i++)
#pragma unroll
        for (int j = 0; j < 4; j++) acc[i][j] = fz;

    for (int kb = 0; kb < 1024; kb += 64) {
#pragma unroll
        for (int t = 0; t < 4; t++) {
            int c = (wv * 4 + t) * 64 + ln;
            int row = c >> 3, gcol = (c & 7) ^ (row & 7);
            gld_lds16(Mn2 + (size_t)(otile + row) * 1024 + kb + gcol * 8, smB + c * 16);
            gld_lds16(Pin + (size_t)(rtile + row) * 1024 + kb + gcol * 8, smA + c * 16);
        }
        __syncthreads();

#pragma unroll
        for (int kk = 0; kk < 2; kk++) {
            const int oct = kk * 4 + lq;
            f16x8 af[4], bfr[4];
#pragma unroll
            for (int i = 0; i < 4; i++) {
                int rrow = wm * 64 + i * 16 + lr;
                af[i] = *(const f16x8*)(smA + rrow * 128 + (oct ^ (rrow & 7)) * 16);
            }
#pragma unroll
            for (int j = 0; j < 4; j++) {
                int brow = wn_ * 64 + j * 16 + lr;
                bfr[j] = *(const f16x8*)(smB + brow * 128 + (oct ^ (brow & 7)) * 16);
            }
#pragma unroll
            for (int i = 0; i < 4; i++)
#pragma unroll
                for (int j = 0; j < 4; j++)
                    acc[i][j] = __builtin_amdgcn_mfma_f32_16x16x32_f16(
                        af[i], bfr[j], acc[i][j], 0, 0, 0);
        }
        __syncthreads();
    }

    // epilogue: quad = 4 colors of cell n at column o
#pragma unroll
    for (int i = 0; i < 4; i++) {
        int rbase = rtile + wm * 64 + i * 16 + lq * 4;
#pragma unroll
        for (int j = 0; j < 4; j++) {
            int o = otile + wn_ * 64 + j * 16 + lr;
            f32x4 a = acc[i][j];
            int n = rbase >> 2;
            size_t no = (size_t)n * PIX + o;
            int c = board[no];
            float asel = (c == 1) ? a[0] : (c == 2) ? a[1] : (c == 3) ? a[2] : a[3];
            float E = (float)En[no];
            float Lnew = (c > 0) ? ((float)Lsel[no] + E + asel) : 0.f;
            float s = 1.f / (1.f + __expf(-Lnew));
            if (MODE == 4) {
                feat[no] = (f16)s;
            } else {
                Lsel[no] = (f16)Lnew;
                f16 sh = (f16)s;
                size_t r0 = (size_t)rbase * PIX + o;
                Pout[r0]           = NC[r0] * sh;
                Pout[r0 + PIX]     = NC[r0 + PIX] * sh;
                Pout[r0 + 2 * PIX] = NC[r0 + 2 * PIX] * sh;
                Pout[r0 + 3 * PIX] = NC[r0 + 3 * PIX] * sh;
            }
        }
    }
}

// ---------------------------------------------------------------------------
// MLP: X1 = leaky(feat @ W1b^T) per 128-batch block, layers 2+3 fused
// in-block via LDS (two 64-batch passes; xs stride 101; W2 in f16).
// ---------------------------------------------------------------------------
__global__ void __launch_bounds__(256) gemm_mlp_fused(
    const f16* __restrict__ feat, const f16* __restrict__ W1b,
    const float* __restrict__ W2, const float* __restrict__ W3,
    float* __restrict__ out) {
    __shared__ __attribute__((aligned(16))) char smem[47360];
    char* smB = smem;
    char* smA = smem + 16384;

    const int tid = threadIdx.x;
    const int wv = tid >> 6, ln = tid & 63;
    const int wm = wv >> 1, wn_ = wv & 1;
    const int lr = ln & 15, lq = ln >> 4;
    const int rtile = blockIdx.x * 128;            // 32 blocks

    const f32x4 fz = {0.f, 0.f, 0.f, 0.f};
    f32x4 acc[4][4];
#pragma unroll
    for (int i = 0; i < 4; i++)
#pragma unroll
        for (int j = 0; j < 4; j++) acc[i][j] = fz;

    for (int kb = 0; kb < 1024; kb += 64) {
#pragma unroll
        for (int t = 0; t < 4; t++) {
            int c = (wv * 4 + t) * 64 + ln;
            int row = c >> 3, gcol = (c & 7) ^ (row & 7);
            gld_lds16(W1b  + (size_t)row * 1024 + kb + gcol * 8, smB + c * 16);
            gld_lds16(feat + (size_t)(rtile + row) * 1024 + kb + gcol * 8, smA + c * 16);
        }
        __syncthreads();
#pragma unroll
        for (int kk = 0; kk < 2; kk++) {
            const int oct = kk * 4 + lq;
            f16x8 af[4], bfr[4];
#pragma unroll
            for (int i = 0; i < 4; i++) {
                int rrow = wm * 64 + i * 16 + lr;
                af[i] = *(const f16x8*)(smA + rrow * 128 + (oct ^ (rrow & 7)) * 16);
            }
#pragma unroll
            for (int j = 0; j < 4; j++) {
                int brow = wn_ * 64 + j * 16 + lr;
                bfr[j] = *(const f16x8*)(smB + brow * 128 + (oct ^ (brow & 7)) * 16);
            }
#pragma unroll
            for (int i = 0; i < 4; i++)
#pragma unroll
                for (int j = 0; j < 4; j++)
                    acc[i][j] = __builtin_amdgcn_mfma_f32_16x16x32_f16(
                        af[i], bfr[j], acc[i][j], 0, 0, 0);
        }
        __syncthreads();
    }

    // ---- fused layers 2+3 ----
    float* xs  = (float*)smem;                     // [64][101]
    f16*   sW2 = (f16*)(smem + 25856);             // [100][100]
    float* sW3 = (float*)(smem + 45856);           // [100]
    float* red = (float*)(smem + 46272);           // [256]
    for (int idx = tid; idx < 10000; idx += 256) sW2[idx] = (f16)W2[idx];
    if (tid < 100) sW3[tid] = W3[tid];

    for (int half = 0; half < 2; half++) {
        if (wm == half) {
#pragma unroll
            for (int i = 0; i < 4; i++) {
                int rb = i * 16 + lq * 4;
#pragma unroll
                for (int j = 0; j < 4; j++) {
                    int o = wn_ * 64 + j * 16 + lr;
                    if (o < 100) {
                        f32x4 a = acc[i][j];
#pragma unroll
                        for (int v = 0; v < 4; v++) {
                            float x = a[v];
                            xs[(rb + v) * 101 + o] = x > 0.f ? x : 0.2f * x;
                        }
                    }
                }
            }
        }
        __syncthreads();
        int nb = tid >> 2, q = tid & 3;
        const float* xrow = xs + nb * 101;
        float partial = 0.f;
        for (int jj = 0; jj < 25; jj++) {
            int j = q + jj * 4;
            const f16* w2r = sW2 + j * 100;
            float a2 = 0.f;
#pragma unroll
            for (int i = 0; i < 100; i++) a2 += (float)w2r[i] * xrow[i];
            partial += sW3[j] * (a2 > 0.f ? a2 : 0.2f * a2);
        }
        red[tid] = partial;
        __syncthreads();
        if (q == 0)
            out[rtile + half * 64 + nb] = red[tid] + red[tid + 1] + red[tid + 2] + red[tid + 3];
        __syncthreads();
    }
}

extern "C" void kernel_launch(void* const* d_in, const int* in_sizes, int n_in,
                              void* d_out, int out_size, void* d_ws, size_t ws_size,
                              hipStream_t stream) {
    (void)in_sizes; (void)n_in; (void)out_size; (void)ws_size;
    const int*   dots   = (const int*)d_in[0];
    const float* w_each = (const float*)d_in[1];
    const float* w_not  = (const float*)d_in[2];
    const float* w_not2 = (const float*)d_in[3];
    const float* w_emp  = (const float*)d_in[4];
    const float* W1 = (const float*)d_in[5];
    const float* W2 = (const float*)d_in[6];
    const float* W3 = (const float*)d_in[7];
    float* out = (float*)d_out;

    char* ws = (char*)d_ws;
    size_t off = 0;
    auto alloc = [&](size_t bytes) -> char* {
        char* p = ws + off;
        off += (bytes + 255) & ~(size_t)255;
        return p;
    };
    f16* Me    = (f16*)alloc((size_t)PIX * PIX * 2);
    f16* Mn    = (f16*)alloc((size_t)PIX * PIX * 2);
    f16* Mn2   = (f16*)alloc((size_t)PIX * PIX * 2);
    f16* Mem   = (f16*)alloc((size_t)PIX * PIX * 2);
    f16* W1b   = (f16*)alloc((size_t)128 * PIX * 2);
    unsigned char* board = (unsigned char*)alloc((size_t)NB * PIX);
    f16* Xe    = (f16*)alloc((size_t)MR * PIX * 2);
    f16* Xn    = (f16*)alloc((size_t)MR * PIX * 2);
    f16* Xz    = (f16*)alloc((size_t)NB * PIX * 2);
    f16* NC    = (f16*)alloc((size_t)MR * PIX * 2);
    f16* En    = (f16*)alloc((size_t)NB * PIX * 2);
    f16* Pa    = (f16*)alloc((size_t)MR * PIX * 2);
    f16* Pb    = (f16*)alloc((size_t)MR * PIX * 2);
    f16* feat  = (f16*)alloc((size_t)NB * PIX * 2);
    f16* Lsel  = (f16*)alloc((size_t)NB * PIX * 2);

    dim3 blk(256);
    // all precompute in one dispatch (mats, W1 pad, board + one-hot arrays)
    build_all<<<5632, blk, 0, stream>>>(w_each, w_not, w_not2, w_emp, W1, dots,
                                        Me, Mn, Mn2, Mem, W1b, board, Xe, Xn, Xz);
    // Phase A-a: NC (A=Xn) + En (A=Xz), pure-async
    gemm_faA<<<1280, blk, 0, stream>>>(Xn, Xz, Mn, Mem, NC, En);
    // Phase A-b: stage1 (A=Xe) with fused mk_sa epilogue -> Lsel, P1
    gemm_faB<<<1024, blk, 0, stream>>>(Xe, Me, board, En, NC, Lsel, Pa);
    // depth 1..3: pure-async GEMM; epilogue emits P_{d+1}
    gemm_depth<3><<<1024, blk, 0, stream>>>(Pa, Mn2, board, NC, En, Lsel, Pb, nullptr);
    gemm_depth<3><<<1024, blk, 0, stream>>>(Pb, Mn2, board, NC, En, Lsel, Pa, nullptr);
    gemm_depth<3><<<1024, blk, 0, stream>>>(Pa, Mn2, board, NC, En, Lsel, Pb, nullptr);
    // depth 4 -> feat
    gemm_depth<4><<<1024, blk, 0, stream>>>(Pb, Mn2, board, NC, En, Lsel, nullptr, feat);
    // MLP 1+2+3 fused
    gemm_mlp_fused<<<32, blk, 0, stream>>>(feat, W1b, W2, W3, out);
}